// Round 21
// baseline (333.808 us; speedup 1.0000x reference)
//
#include <hip/hip_runtime.h>

typedef short short8 __attribute__((ext_vector_type(8)));
typedef float f32x4 __attribute__((ext_vector_type(4)));
typedef float f32x16 __attribute__((ext_vector_type(16)));
typedef unsigned int u32x4 __attribute__((ext_vector_type(4)));

#define B_   4
#define N_   2048
#define D_   2048
#define H_   16
#define HD_  128
#define M_   (B_ * N_)   // 8192
#define KVC  256         // kv projection cols (k 0..127 | v 128..255)
#define NQKV (D_ + KVC)  // 2304 fused output cols

__device__ __forceinline__ unsigned short f2bf(float f) {
  unsigned u = __builtin_bit_cast(unsigned, f);
  u = (u + 0x7FFFu + ((u >> 16) & 1u)) >> 16;   // RNE, finite inputs only
  return (unsigned short)u;
}

__device__ __forceinline__ void gl2lds16(const void* g, void* l) {
  __builtin_amdgcn_global_load_lds((const __attribute__((address_space(1))) void*)g,
                                   (__attribute__((address_space(3))) void*)l,
                                   16, 0, 0);
}

__device__ __forceinline__ unsigned cvt_pk_bf16(float lo, float hi) {
  unsigned r;
  asm volatile("v_cvt_pk_bf16_f32 %0, %1, %2" : "=v"(r) : "v"(lo), "v"(hi));
  return r;
}

#define BAR   do { __builtin_amdgcn_sched_barrier(0); __builtin_amdgcn_s_barrier(); \
                   __builtin_amdgcn_sched_barrier(0); } while (0)

// ---------------- elementwise f32 -> bf16 ----------------
__global__ __launch_bounds__(256) void cvt_bf16_kernel(const float* __restrict__ in,
                                                       unsigned short* __restrict__ out,
                                                       int n8) {
  int i = blockIdx.x * 256 + threadIdx.x;
  if (i >= n8) return;
  float4 a = ((const float4*)in)[i * 2];
  float4 b = ((const float4*)in)[i * 2 + 1];
  u32x4 u;
  u[0] = cvt_pk_bf16(a.x, a.y);
  u[1] = cvt_pk_bf16(a.z, a.w);
  u[2] = cvt_pk_bf16(b.x, b.y);
  u[3] = cvt_pk_bf16(b.z, b.w);
  ((short8*)out)[i] = __builtin_bit_cast(short8, u);
}

// ------- fused f32 [R][C] -> bf16 [C][R] for Wq | Wkv | Wo (one launch) -------
__global__ __launch_bounds__(256) void transpose_cvt3(const float* __restrict__ Wq,
                                                      const float* __restrict__ Wkv,
                                                      const float* __restrict__ Wo,
                                                      unsigned short* __restrict__ wqt,
                                                      unsigned short* __restrict__ wkvt,
                                                      unsigned short* __restrict__ wot) {
  __shared__ float tile[64][65];
  const float* in; unsigned short* out; int C, cy;
  if (blockIdx.y < 32)      { in = Wq;  out = wqt;  C = D_;  cy = blockIdx.y; }
  else if (blockIdx.y < 36) { in = Wkv; out = wkvt; C = KVC; cy = blockIdx.y - 32; }
  else                      { in = Wo;  out = wot;  C = D_;  cy = blockIdx.y - 36; }
  const int R = D_;
  int r0 = blockIdx.x * 64, c0 = cy * 64;
  int t = threadIdx.x;
  int tr = t >> 4, tc4 = (t & 15) * 4;
#pragma unroll
  for (int it = 0; it < 4; ++it) {
    int r = it * 16 + tr;
    float4 v = *(const float4*)(in + (size_t)(r0 + r) * C + c0 + tc4);
    tile[r][tc4 + 0] = v.x; tile[r][tc4 + 1] = v.y;
    tile[r][tc4 + 2] = v.z; tile[r][tc4 + 3] = v.w;
  }
  __syncthreads();
#pragma unroll
  for (int it = 0; it < 4; ++it) {
    int oc = it * 16 + tr;   // input col = output row
    ushort4 o;
    o.x = f2bf(tile[tc4 + 0][oc]);
    o.y = f2bf(tile[tc4 + 1][oc]);
    o.z = f2bf(tile[tc4 + 2][oc]);
    o.w = f2bf(tile[tc4 + 3][oc]);
    *(ushort4*)(out + (size_t)(c0 + oc) * R + r0 + tc4) = o;
  }
}

// ---------------- bf16 v-slice of kv -> v^T [b][128][2048], t pre-permuted by pi ----
__global__ __launch_bounds__(256) void transpose_v(const unsigned short* __restrict__ kv,
                                                   unsigned short* __restrict__ vt) {
  __shared__ unsigned short tile[64][72];
  int t0 = blockIdx.x * 64, d0 = blockIdx.y * 64, b = blockIdx.z;
  int tid = threadIdx.x;
  int tr = tid >> 3, tc8 = (tid & 7) * 8;
#pragma unroll
  for (int it = 0; it < 2; ++it) {
    int r = it * 32 + tr;
    short8 v = *(const short8*)(kv + (size_t)(b * N_ + t0 + r) * KVC + HD_ + d0 + tc8);
#pragma unroll
    for (int j = 0; j < 8; ++j) tile[r][tc8 + j] = (unsigned short)v[j];
  }
  __syncthreads();
  int beta0 = tc8 >> 2, beta1 = beta0 + 1;
  int p0 = (((beta0 & 3) == 1) || ((beta0 & 3) == 2)) ? (beta0 ^ 3) : beta0;
  int p1 = (((beta1 & 3) == 1) || ((beta1 & 3) == 2)) ? (beta1 ^ 3) : beta1;
#pragma unroll
  for (int it = 0; it < 2; ++it) {
    int od = it * 32 + tr;
    ushort4 lo, hi4;
#pragma unroll
    for (int j = 0; j < 4; ++j) {
      ((unsigned short*)&lo)[j]  = tile[tc8 + j][od];
      ((unsigned short*)&hi4)[j] = tile[tc8 + 4 + j][od];
    }
    unsigned short* base = vt + (size_t)(b * HD_ + d0 + od) * N_ + t0;
    *(ushort4*)(base + p0 * 4) = lo;
    *(ushort4*)(base + p1 * 4) = hi4;
  }
}

// ============ 256x256 8-phase GEMM (T2+T3+T4+T5), C = A @ Bt^T ============
// 8 waves (2M x 4N), BK=64, LDS 128KB double-buffered. Counted vmcnt(4) at phases
// 1/5 only. R21 change: NO forced lgkmcnt(0)/sched_barrier before MFMA — the
// ds_reads are compiler-visible loads, so hipcc emits counted lgkmcnt interleave
// (m141: forced-order pinning defeats the scheduler). Barriers + vmcnt fences kept.
template <int MODE>   // 0: qkv (bf16 out, col-routed q/kv)   1: fp32 out
__global__ __launch_bounds__(512, 2) void gemm256(const unsigned short* __restrict__ A,
                                                  const unsigned short* __restrict__ Bt,
                                                  unsigned short* __restrict__ qb,
                                                  unsigned short* __restrict__ kvb,
                                                  float* __restrict__ fout,
                                                  float sq) {
  constexpr int BK = 64, K = D_, NT = K / BK;   // 32 K-tiles
  __shared__ __align__(16) unsigned short lds[2][4][128 * 64];   // 128 KB
  const int tid = threadIdx.x;
  const int lane = tid & 63;
  const int w = tid >> 6;               // 8 waves
  const int wr = w >> 2, wc = w & 3;    // 2 x 4
  const int l15 = lane & 15, lg = lane >> 4;
  const int row0 = blockIdx.y * 256, col0 = blockIdx.x * 256;

  f32x4 acc[8][4] = {};
  short8 bf[8];   // B fragments: held across the 4 phases of a K-tile
  short8 af[4];   // A fragments: per-phase quad

  auto stage = [&](int buf, int kind, int t) {   // kind: 0,1=A half; 2,3=B half
    const unsigned short* src = (kind < 2) ? A : Bt;
    const int base = (kind < 2) ? (row0 + kind * 128) : (col0 + (kind - 2) * 128);
#pragma unroll
    for (int ld = 0; ld < 2; ++ld) {
      int e = ld * 512 + tid;
      int r = e >> 3, c = e & 7;
      int csw = c ^ (r & 7);
      gl2lds16(src + (size_t)(base + r) * K + t * BK + csw * 8,
               &lds[buf][kind][(e - lane) * 8]);
    }
  };
  auto readB = [&](int buf) {
#pragma unroll
    for (int n = 0; n < 4; ++n)
#pragma unroll
      for (int kk = 0; kk < 2; ++kk) {
        int row = (wc & 1) * 64 + n * 16 + l15;
        int ch = (kk * 4 + lg) ^ (row & 7);
        bf[n * 2 + kk] = *(const short8*)&lds[buf][2 + (wc >> 1)][row * 64 + ch * 8];
      }
  };
  auto readA = [&](int buf, int q) {
#pragma unroll
    for (int mi = 0; mi < 2; ++mi)
#pragma unroll
      for (int kk = 0; kk < 2; ++kk) {
        int row = (q * 2 + mi) * 16 + l15;
        int ch = (kk * 4 + lg) ^ (row & 7);
        af[mi * 2 + kk] = *(const short8*)&lds[buf][wr][row * 64 + ch * 8];
      }
  };
  auto mfmaQ = [&](int q) {
    __builtin_amdgcn_s_setprio(1);
#pragma unroll
    for (int mi = 0; mi < 2; ++mi)
#pragma unroll
      for (int n = 0; n < 4; ++n)
#pragma unroll
        for (int kk = 0; kk < 2; ++kk)
          acc[q * 2 + mi][n] = __builtin_amdgcn_mfma_f32_16x16x32_bf16(
              af[mi * 2 + kk], bf[n * 2 + kk], acc[q * 2 + mi][n], 0, 0, 0);
    __builtin_amdgcn_s_setprio(0);
  };

  // prologue: tile0 all 4 halves (8 loads), then tile1 B halves (4 loads)
  stage(0, 0, 0); stage(0, 1, 0); stage(0, 2, 0); stage(0, 3, 0);
  stage(1, 2, 1); stage(1, 3, 1);

  for (int t = 0; t < NT; t += 2) {
    const bool gY = (t + 2 < NT), gZ = (t + 3 < NT);
    // ---- phase 1 (tile t, buf0, quad 0) ----
    asm volatile("s_waitcnt vmcnt(4)" ::: "memory");
    BAR;
    stage(1, 0, t + 1);
    readB(0); readA(0, 0);
    mfmaQ(0); BAR;
    // ---- phase 2 ----
    stage(1, 1, t + 1);
    readA(0, 1); mfmaQ(1); BAR;
    // ---- phase 3 ----
    if (gY) stage(0, 2, t + 2);
    readA(0, 2); mfmaQ(2); BAR;
    // ---- phase 4 ----
    if (gY) stage(0, 3, t + 2);
    readA(0, 3); mfmaQ(3); BAR;
    // ---- phase 5 (tile t+1, buf1, quad 0) ----
    if (gZ) { asm volatile("s_waitcnt vmcnt(4)" ::: "memory"); }
    else    { asm volatile("s_waitcnt vmcnt(0)" ::: "memory"); }
    BAR;
    if (gY) stage(0, 0, t + 2);
    readB(1); readA(1, 0);
    mfmaQ(0); BAR;
    // ---- phase 6 ----
    if (gY) stage(0, 1, t + 2);
    readA(1, 1); mfmaQ(1); BAR;
    // ---- phase 7 ----
    if (gZ) stage(1, 2, t + 3);
    readA(1, 2); mfmaQ(2); BAR;
    // ---- phase 8 ----
    if (gZ) stage(1, 3, t + 3);
    readA(1, 3); mfmaQ(3); BAR;
  }

  // ---- epilogue ----
  if (MODE == 0) {
    const bool isq = (col0 < D_);
    unsigned short* outp = isq ? qb : kvb;
    const int ncols = isq ? D_ : KVC;
    const int cbase = isq ? col0 : 0;
    const float sc = isq ? sq : 1.0f;
#pragma unroll
    for (int m = 0; m < 8; ++m)
#pragma unroll
      for (int n = 0; n < 4; ++n)
#pragma unroll
        for (int r = 0; r < 4; ++r) {
          int row = row0 + wr * 128 + m * 16 + lg * 4 + r;
          int col = cbase + wc * 64 + n * 16 + l15;
          outp[(size_t)row * ncols + col] = f2bf(acc[m][n][r] * sc);
        }
  } else {
#pragma unroll
    for (int m = 0; m < 8; ++m)
#pragma unroll
      for (int n = 0; n < 4; ++n)
#pragma unroll
        for (int r = 0; r < 4; ++r) {
          int row = row0 + wr * 128 + m * 16 + lg * 4 + r;
          int col = col0 + wc * 64 + n * 16 + l15;
          fout[(size_t)row * D_ + col] = acc[m][n][r];
        }
  }
}

// ---------------- flash attention (MQA), 32x32 swapped-QK^T, 4 waves/block ----------
// Frozen R20 state (T4 counted-vmcnt dbuf; six schedule variants all 154-160us).
__global__ __launch_bounds__(256, 2) void attn_kernel(const unsigned short* __restrict__ Q,
                                                      const unsigned short* __restrict__ KV,
                                                      const unsigned short* __restrict__ VT,
                                                      unsigned short* __restrict__ Y) {
  __shared__ __align__(16) unsigned short Ks[2][64 * HD_];   // [t][d] 16KB each, chunk^=(t&7)
  __shared__ __align__(16) unsigned short Vs[2][HD_ * 64];   // [d][t] 16KB each, chunk^=(d&7)
  const int tid = threadIdx.x;
  const int lane = tid & 63, w = tid >> 6;                // 4 waves
  const int l31 = lane & 31, hi = lane >> 5;
  const int ksw = l31 & 7;
  const int qt = blockIdx.x, h = blockIdx.y, b = blockIdx.z;
  const int q0 = qt * 128 + w * 32;        // warp's 32 q-rows

  short8 qf[8];
  {
    const unsigned short* qp = Q + (size_t)(b * N_ + q0 + l31) * D_ + h * HD_ + hi * 8;
#pragma unroll
    for (int kk = 0; kk < 8; ++kk) qf[kk] = *(const short8*)(qp + kk * 16);
  }

  f32x16 o[4] = {};
  float l_r = 0.f;

  auto stage = [&](int buf, int t0) {
#pragma unroll
    for (int s = 0; s < 4; ++s) {
      int e = s * 256 + tid;
      int r = e >> 4, c = e & 15;
      int csw = c ^ (r & 7);
      gl2lds16(KV + (size_t)(b * N_ + t0 + r) * KVC + csw * 8, &Ks[buf][(e - lane) * 8]);
    }
#pragma unroll
    for (int s = 0; s < 4; ++s) {
      int e = s * 256 + tid;
      int r = e >> 3, c = e & 7;
      int csw = c ^ (r & 7);
      gl2lds16(VT + (size_t)(b * HD_ + r) * N_ + t0 + csw * 8, &Vs[buf][(e - lane) * 8]);
    }
  };

  stage(0, 0);
  stage(1, 64);
  int cur = 0;

  for (int t0 = 0; t0 < N_; t0 += 64) {
    if (t0 + 64 < N_) { asm volatile("s_waitcnt vmcnt(8)" ::: "memory"); }
    else              { asm volatile("s_waitcnt vmcnt(0)" ::: "memory"); }
    BAR;

    f32x16 s0 = {}, s1 = {};
    __builtin_amdgcn_s_setprio(1);
#pragma unroll
    for (int kk = 0; kk < 8; ++kk) {
      int ch = ((2 * kk + hi) ^ ksw) * 8;
      short8 kf0 = *(const short8*)&Ks[cur][(l31) * HD_ + ch];
      short8 kf1 = *(const short8*)&Ks[cur][(32 + l31) * HD_ + ch];
      s0 = __builtin_amdgcn_mfma_f32_32x32x16_bf16(kf0, qf[kk], s0, 0, 0, 0);
      s1 = __builtin_amdgcn_mfma_f32_32x32x16_bf16(kf1, qf[kk], s1, 0, 0, 0);
    }
    __builtin_amdgcn_s_setprio(0);

#pragma unroll
    for (int r = 0; r < 16; ++r) {
      s0[r] = __builtin_amdgcn_exp2f(s0[r]);
      s1[r] = __builtin_amdgcn_exp2f(s1[r]);
    }
    float tsum[16];
#pragma unroll
    for (int r = 0; r < 16; ++r) tsum[r] = s0[r] + s1[r];
#pragma unroll
    for (int st = 8; st > 0; st >>= 1)
#pragma unroll
      for (int i = 0; i < 8; ++i) if (i < st) tsum[i] += tsum[i + st];
    l_r += tsum[0] + __shfl_xor(tsum[0], 32);

    unsigned pw0[8], pw1[8];
#pragma unroll
    for (int j = 0; j < 8; ++j) {
      pw0[j] = cvt_pk_bf16(s0[2 * j], s0[2 * j + 1]);
      pw1[j] = cvt_pk_bf16(s1[2 * j], s1[2 * j + 1]);
    }
    short8 paf[4];
    { u32x4 u; u[0]=pw0[0]; u[1]=pw0[1]; u[2]=pw0[2]; u[3]=pw0[3]; paf[0]=__builtin_bit_cast(short8,u); }
    { u32x4 u; u[0]=pw0[4]; u[1]=pw0[5]; u[2]=pw0[6]; u[3]=pw0[7]; paf[1]=__builtin_bit_cast(short8,u); }
    { u32x4 u; u[0]=pw1[0]; u[1]=pw1[1]; u[2]=pw1[2]; u[3]=pw1[3]; paf[2]=__builtin_bit_cast(short8,u); }
    { u32x4 u; u[0]=pw1[4]; u[1]=pw1[5]; u[2]=pw1[6]; u[3]=pw1[7]; paf[3]=__builtin_bit_cast(short8,u); }

    __builtin_amdgcn_s_setprio(1);
#pragma unroll
    for (int ts2 = 0; ts2 < 4; ++ts2) {
#pragma unroll
      for (int dn = 0; dn < 4; ++dn) {
        int row = dn * 32 + l31;
        int ch = ((2 * ts2 + hi) ^ (row & 7)) * 8;
        short8 vf = *(const short8*)&Vs[cur][row * 64 + ch];
        o[dn] = __builtin_amdgcn_mfma_f32_32x32x16_bf16(paf[ts2], vf, o[dn], 0, 0, 0);
      }
    }
    __builtin_amdgcn_s_setprio(0);

    BAR;
    if (t0 + 128 < N_) stage(cur, t0 + 128);
    cur ^= 1;
  }

  float linv = 1.0f / l_r;
#pragma unroll
  for (int r = 0; r < 16; ++r) {
    int qrow = (r & 3) + 8 * (r >> 2) + 4 * hi;
    float li = __shfl(linv, qrow);
    size_t rowg = (size_t)(b * N_ + q0 + qrow) * D_ + h * HD_;
#pragma unroll
    for (int dn = 0; dn < 4; ++dn)
      Y[rowg + dn * 32 + l31] = f2bf(o[dn][r] * li);
  }
}

extern "C" void kernel_launch(void* const* d_in, const int* in_sizes, int n_in,
                              void* d_out, int out_size, void* d_ws, size_t ws_size,
                              hipStream_t stream) {
  const float* x   = (const float*)d_in[0];
  const float* Wq  = (const float*)d_in[1];
  const float* Wkv = (const float*)d_in[2];
  const float* Wo  = (const float*)d_in[3];

  unsigned char* ws = (unsigned char*)d_ws;
  size_t off = 0;
  auto alloc = [&](size_t bytes) { void* p = ws + off; off += bytes; return p; };
  unsigned short* xb   = (unsigned short*)alloc((size_t)M_ * D_ * 2);   // reused as y
  unsigned short* wqt  = (unsigned short*)alloc((size_t)D_ * D_ * 2);   // [2048][2048]
  unsigned short* wkvt = (unsigned short*)alloc((size_t)KVC * D_ * 2);  // adjacent rows 2048..2303
  unsigned short* wot  = (unsigned short*)alloc((size_t)D_ * D_ * 2);
  unsigned short* qb   = (unsigned short*)alloc((size_t)M_ * D_ * 2);
  unsigned short* kvb  = (unsigned short*)alloc((size_t)M_ * KVC * 2);
  unsigned short* vt   = (unsigned short*)alloc((size_t)B_ * HD_ * N_ * 2);
  (void)ws_size; (void)in_sizes; (void)n_in; (void)out_size;

  cvt_bf16_kernel<<<(M_ * D_ / 8 + 255) / 256, 256, 0, stream>>>(x, xb, M_ * D_ / 8);
  transpose_cvt3<<<dim3(32, 68), 256, 0, stream>>>(Wq, Wkv, Wo, wqt, wkvt, wot);

  // (1/sqrt(128)) * log2(e): softmax runs in log2 domain inside attn_kernel
  const float scale = 0.12751743f;
  gemm256<0><<<dim3(NQKV / 256, M_ / 256), 512, 0, stream>>>(xb, wqt, qb, kvb, nullptr, scale);
  transpose_v<<<dim3(N_ / 64, HD_ / 64, B_), 256, 0, stream>>>(kvb, vt);

  unsigned short* yb = xb;  // xb dead after gemm256<0>
  attn_kernel<<<dim3(N_ / 128, H_, B_), 256, 0, stream>>>(qb, kvb, vt, yb);

  gemm256<1><<<dim3(D_ / 256, M_ / 256), 512, 0, stream>>>(yb, wot, nullptr, nullptr,
                                                           (float*)d_out, 1.0f);
}

// Round 22
// 326.012 us; speedup vs baseline: 1.0239x; 1.0239x over previous
//
#include <hip/hip_runtime.h>

typedef short short8 __attribute__((ext_vector_type(8)));
typedef float f32x4 __attribute__((ext_vector_type(4)));
typedef float f32x16 __attribute__((ext_vector_type(16)));
typedef unsigned int u32x4 __attribute__((ext_vector_type(4)));

#define B_   4
#define N_   2048
#define D_   2048
#define H_   16
#define HD_  128
#define M_   (B_ * N_)   // 8192
#define KVC  256         // kv projection cols (k 0..127 | v 128..255)
#define NQKV (D_ + KVC)  // 2304 fused output cols

__device__ __forceinline__ unsigned short f2bf(float f) {
  unsigned u = __builtin_bit_cast(unsigned, f);
  u = (u + 0x7FFFu + ((u >> 16) & 1u)) >> 16;   // RNE, finite inputs only
  return (unsigned short)u;
}

__device__ __forceinline__ void gl2lds16(const void* g, void* l) {
  __builtin_amdgcn_global_load_lds((const __attribute__((address_space(1))) void*)g,
                                   (__attribute__((address_space(3))) void*)l,
                                   16, 0, 0);
}

__device__ __forceinline__ unsigned cvt_pk_bf16(float lo, float hi) {
  unsigned r;
  asm volatile("v_cvt_pk_bf16_f32 %0, %1, %2" : "=v"(r) : "v"(lo), "v"(hi));
  return r;
}

#define LGKM0 do { asm volatile("s_waitcnt lgkmcnt(0)" ::: "memory"); \
                   __builtin_amdgcn_sched_barrier(0); } while (0)
#define BAR   do { __builtin_amdgcn_sched_barrier(0); __builtin_amdgcn_s_barrier(); \
                   __builtin_amdgcn_sched_barrier(0); } while (0)

// ---------------- elementwise f32 -> bf16 ----------------
__global__ __launch_bounds__(256) void cvt_bf16_kernel(const float* __restrict__ in,
                                                       unsigned short* __restrict__ out,
                                                       int n8) {
  int i = blockIdx.x * 256 + threadIdx.x;
  if (i >= n8) return;
  float4 a = ((const float4*)in)[i * 2];
  float4 b = ((const float4*)in)[i * 2 + 1];
  u32x4 u;
  u[0] = cvt_pk_bf16(a.x, a.y);
  u[1] = cvt_pk_bf16(a.z, a.w);
  u[2] = cvt_pk_bf16(b.x, b.y);
  u[3] = cvt_pk_bf16(b.z, b.w);
  ((short8*)out)[i] = __builtin_bit_cast(short8, u);
}

// ------- fused f32 [R][C] -> bf16 [C][R] for Wq | Wkv | Wo (one launch) -------
__global__ __launch_bounds__(256) void transpose_cvt3(const float* __restrict__ Wq,
                                                      const float* __restrict__ Wkv,
                                                      const float* __restrict__ Wo,
                                                      unsigned short* __restrict__ wqt,
                                                      unsigned short* __restrict__ wkvt,
                                                      unsigned short* __restrict__ wot) {
  __shared__ float tile[64][65];
  const float* in; unsigned short* out; int C, cy;
  if (blockIdx.y < 32)      { in = Wq;  out = wqt;  C = D_;  cy = blockIdx.y; }
  else if (blockIdx.y < 36) { in = Wkv; out = wkvt; C = KVC; cy = blockIdx.y - 32; }
  else                      { in = Wo;  out = wot;  C = D_;  cy = blockIdx.y - 36; }
  const int R = D_;
  int r0 = blockIdx.x * 64, c0 = cy * 64;
  int t = threadIdx.x;
  int tr = t >> 4, tc4 = (t & 15) * 4;
#pragma unroll
  for (int it = 0; it < 4; ++it) {
    int r = it * 16 + tr;
    float4 v = *(const float4*)(in + (size_t)(r0 + r) * C + c0 + tc4);
    tile[r][tc4 + 0] = v.x; tile[r][tc4 + 1] = v.y;
    tile[r][tc4 + 2] = v.z; tile[r][tc4 + 3] = v.w;
  }
  __syncthreads();
#pragma unroll
  for (int it = 0; it < 4; ++it) {
    int oc = it * 16 + tr;   // input col = output row
    ushort4 o;
    o.x = f2bf(tile[tc4 + 0][oc]);
    o.y = f2bf(tile[tc4 + 1][oc]);
    o.z = f2bf(tile[tc4 + 2][oc]);
    o.w = f2bf(tile[tc4 + 3][oc]);
    *(ushort4*)(out + (size_t)(c0 + oc) * R + r0 + tc4) = o;
  }
}

// ============ 256x256 8-phase GEMM (T2+T3+T4+T5), C = A @ Bt^T ============
// 8 waves (2M x 4N), BK=64, LDS 128KB double-buffered. Counted vmcnt(4) at phases
// 1/5 only (never 0 mid-loop). T2 swizzle: chunk c at row r <- c^(r&7) both sides.
// MODE 0 epilogue additionally FUSES transpose_v: the kv block's v-columns
// (col 128..255) are written directly to vt[b][d][t] with the pi 4-block
// permutation (each lane's acc[m][n][0..3] spans exactly one aligned 4-block of t).
template <int MODE>   // 0: qkv (q scaled -> qb; k -> kvb; v -> vt^T)   1: fp32 out
__global__ __launch_bounds__(512, 2) void gemm256(const unsigned short* __restrict__ A,
                                                  const unsigned short* __restrict__ Bt,
                                                  unsigned short* __restrict__ qb,
                                                  unsigned short* __restrict__ kvb,
                                                  unsigned short* __restrict__ vt,
                                                  float* __restrict__ fout,
                                                  float sq) {
  constexpr int BK = 64, K = D_, NT = K / BK;   // 32 K-tiles
  __shared__ __align__(16) unsigned short lds[2][4][128 * 64];   // 128 KB
  const int tid = threadIdx.x;
  const int lane = tid & 63;
  const int w = tid >> 6;               // 8 waves
  const int wr = w >> 2, wc = w & 3;    // 2 x 4
  const int l15 = lane & 15, lg = lane >> 4;
  const int row0 = blockIdx.y * 256, col0 = blockIdx.x * 256;

  f32x4 acc[8][4] = {};
  short8 bf[8];   // B fragments: held across the 4 phases of a K-tile
  short8 af[4];   // A fragments: per-phase quad

  auto stage = [&](int buf, int kind, int t) {   // kind: 0,1=A half; 2,3=B half
    const unsigned short* src = (kind < 2) ? A : Bt;
    const int base = (kind < 2) ? (row0 + kind * 128) : (col0 + (kind - 2) * 128);
#pragma unroll
    for (int ld = 0; ld < 2; ++ld) {
      int e = ld * 512 + tid;
      int r = e >> 3, c = e & 7;
      int csw = c ^ (r & 7);
      gl2lds16(src + (size_t)(base + r) * K + t * BK + csw * 8,
               &lds[buf][kind][(e - lane) * 8]);
    }
  };
  auto readB = [&](int buf) {
#pragma unroll
    for (int n = 0; n < 4; ++n)
#pragma unroll
      for (int kk = 0; kk < 2; ++kk) {
        int row = (wc & 1) * 64 + n * 16 + l15;
        int ch = (kk * 4 + lg) ^ (row & 7);
        bf[n * 2 + kk] = *(const short8*)&lds[buf][2 + (wc >> 1)][row * 64 + ch * 8];
      }
  };
  auto readA = [&](int buf, int q) {
#pragma unroll
    for (int mi = 0; mi < 2; ++mi)
#pragma unroll
      for (int kk = 0; kk < 2; ++kk) {
        int row = (q * 2 + mi) * 16 + l15;
        int ch = (kk * 4 + lg) ^ (row & 7);
        af[mi * 2 + kk] = *(const short8*)&lds[buf][wr][row * 64 + ch * 8];
      }
  };
  auto mfmaQ = [&](int q) {
    __builtin_amdgcn_s_setprio(1);
#pragma unroll
    for (int mi = 0; mi < 2; ++mi)
#pragma unroll
      for (int n = 0; n < 4; ++n)
#pragma unroll
        for (int kk = 0; kk < 2; ++kk)
          acc[q * 2 + mi][n] = __builtin_amdgcn_mfma_f32_16x16x32_bf16(
              af[mi * 2 + kk], bf[n * 2 + kk], acc[q * 2 + mi][n], 0, 0, 0);
    __builtin_amdgcn_s_setprio(0);
  };

  // prologue: tile0 all 4 halves (8 loads), then tile1 B halves (4 loads)
  stage(0, 0, 0); stage(0, 1, 0); stage(0, 2, 0); stage(0, 3, 0);
  stage(1, 2, 1); stage(1, 3, 1);

  for (int t = 0; t < NT; t += 2) {
    const bool gY = (t + 2 < NT), gZ = (t + 3 < NT);
    // ---- phase 1 (tile t, buf0, quad 0) ----
    asm volatile("s_waitcnt vmcnt(4)" ::: "memory");
    BAR;
    stage(1, 0, t + 1);
    readB(0); readA(0, 0);
    LGKM0; mfmaQ(0); BAR;
    // ---- phase 2 ----
    stage(1, 1, t + 1);
    readA(0, 1); LGKM0; mfmaQ(1); BAR;
    // ---- phase 3 ----
    if (gY) stage(0, 2, t + 2);
    readA(0, 2); LGKM0; mfmaQ(2); BAR;
    // ---- phase 4 ----
    if (gY) stage(0, 3, t + 2);
    readA(0, 3); LGKM0; mfmaQ(3); BAR;
    // ---- phase 5 (tile t+1, buf1, quad 0) ----
    if (gZ) { asm volatile("s_waitcnt vmcnt(4)" ::: "memory"); }
    else    { asm volatile("s_waitcnt vmcnt(0)" ::: "memory"); }
    BAR;
    if (gY) stage(0, 0, t + 2);
    readB(1); readA(1, 0);
    LGKM0; mfmaQ(0); BAR;
    // ---- phase 6 ----
    if (gY) stage(0, 1, t + 2);
    readA(1, 1); LGKM0; mfmaQ(1); BAR;
    // ---- phase 7 ----
    if (gZ) stage(1, 2, t + 3);
    readA(1, 2); LGKM0; mfmaQ(2); BAR;
    // ---- phase 8 ----
    if (gZ) stage(1, 3, t + 3);
    readA(1, 3); LGKM0; mfmaQ(3); BAR;
  }

  // ---- epilogue ----
  if (MODE == 0) {
    if (col0 < D_) {
      // q block: scaled bf16 -> qb
#pragma unroll
      for (int m = 0; m < 8; ++m)
#pragma unroll
        for (int n = 0; n < 4; ++n)
#pragma unroll
          for (int r = 0; r < 4; ++r) {
            int row = row0 + wr * 128 + m * 16 + lg * 4 + r;
            int col = col0 + wc * 64 + n * 16 + l15;
            qb[(size_t)row * D_ + col] = f2bf(acc[m][n][r] * sq);
          }
    } else {
      // kv block: k (col<128) -> kvb rows; v (col>=128) -> vt[b][d][t], pi-permuted.
      // trow = b*2048 + t; each lane's r=0..3 spans one aligned 4-block of t.
#pragma unroll
      for (int m = 0; m < 8; ++m) {
        int trow0 = row0 + wr * 128 + m * 16 + lg * 4;
        int b = trow0 >> 11;
        int t4 = (trow0 & 2047) >> 2;          // 4-block index within batch
        int bm = t4 & 3;
        int p = (bm == 1 || bm == 2) ? (t4 ^ 3) : t4;
#pragma unroll
        for (int n = 0; n < 4; ++n) {
          int col = wc * 64 + n * 16 + l15;
          if (col < 128) {
#pragma unroll
            for (int r = 0; r < 4; ++r)
              kvb[(size_t)(trow0 + r) * KVC + col] = f2bf(acc[m][n][r]);
          } else {
            ushort4 v4;
            v4.x = f2bf(acc[m][n][0]); v4.y = f2bf(acc[m][n][1]);
            v4.z = f2bf(acc[m][n][2]); v4.w = f2bf(acc[m][n][3]);
            *(ushort4*)&vt[((size_t)(b * HD_ + col - 128)) * N_ + p * 4] = v4;
          }
        }
      }
    }
  } else {
#pragma unroll
    for (int m = 0; m < 8; ++m)
#pragma unroll
      for (int n = 0; n < 4; ++n)
#pragma unroll
        for (int r = 0; r < 4; ++r) {
          int row = row0 + wr * 128 + m * 16 + lg * 4 + r;
          int col = col0 + wc * 64 + n * 16 + l15;
          fout[(size_t)row * D_ + col] = acc[m][n][r];
        }
  }
}

// ---------------- flash attention (MQA), 32x32 swapped-QK^T, 4 waves/block ----------
// Frozen R20 state (T4 counted-vmcnt dbuf; seven schedule variants all 154-160us).
__global__ __launch_bounds__(256, 2) void attn_kernel(const unsigned short* __restrict__ Q,
                                                      const unsigned short* __restrict__ KV,
                                                      const unsigned short* __restrict__ VT,
                                                      unsigned short* __restrict__ Y) {
  __shared__ __align__(16) unsigned short Ks[2][64 * HD_];   // [t][d] 16KB each, chunk^=(t&7)
  __shared__ __align__(16) unsigned short Vs[2][HD_ * 64];   // [d][t] 16KB each, chunk^=(d&7)
  const int tid = threadIdx.x;
  const int lane = tid & 63, w = tid >> 6;                // 4 waves
  const int l31 = lane & 31, hi = lane >> 5;
  const int ksw = l31 & 7;
  const int qt = blockIdx.x, h = blockIdx.y, b = blockIdx.z;
  const int q0 = qt * 128 + w * 32;        // warp's 32 q-rows

  short8 qf[8];
  {
    const unsigned short* qp = Q + (size_t)(b * N_ + q0 + l31) * D_ + h * HD_ + hi * 8;
#pragma unroll
    for (int kk = 0; kk < 8; ++kk) qf[kk] = *(const short8*)(qp + kk * 16);
  }

  f32x16 o[4] = {};
  float l_r = 0.f;

  auto stage = [&](int buf, int t0) {
#pragma unroll
    for (int s = 0; s < 4; ++s) {
      int e = s * 256 + tid;
      int r = e >> 4, c = e & 15;
      int csw = c ^ (r & 7);
      gl2lds16(KV + (size_t)(b * N_ + t0 + r) * KVC + csw * 8, &Ks[buf][(e - lane) * 8]);
    }
#pragma unroll
    for (int s = 0; s < 4; ++s) {
      int e = s * 256 + tid;
      int r = e >> 3, c = e & 7;
      int csw = c ^ (r & 7);
      gl2lds16(VT + (size_t)(b * HD_ + r) * N_ + t0 + csw * 8, &Vs[buf][(e - lane) * 8]);
    }
  };

  stage(0, 0);
  stage(1, 64);
  int cur = 0;

  for (int t0 = 0; t0 < N_; t0 += 64) {
    if (t0 + 64 < N_) { asm volatile("s_waitcnt vmcnt(8)" ::: "memory"); }
    else              { asm volatile("s_waitcnt vmcnt(0)" ::: "memory"); }
    BAR;

    f32x16 s0 = {}, s1 = {};
    __builtin_amdgcn_s_setprio(1);
#pragma unroll
    for (int kk = 0; kk < 8; ++kk) {
      int ch = ((2 * kk + hi) ^ ksw) * 8;
      short8 kf0 = *(const short8*)&Ks[cur][(l31) * HD_ + ch];
      short8 kf1 = *(const short8*)&Ks[cur][(32 + l31) * HD_ + ch];
      s0 = __builtin_amdgcn_mfma_f32_32x32x16_bf16(kf0, qf[kk], s0, 0, 0, 0);
      s1 = __builtin_amdgcn_mfma_f32_32x32x16_bf16(kf1, qf[kk], s1, 0, 0, 0);
    }
    __builtin_amdgcn_s_setprio(0);

#pragma unroll
    for (int r = 0; r < 16; ++r) {
      s0[r] = __builtin_amdgcn_exp2f(s0[r]);
      s1[r] = __builtin_amdgcn_exp2f(s1[r]);
    }
    float tsum[16];
#pragma unroll
    for (int r = 0; r < 16; ++r) tsum[r] = s0[r] + s1[r];
#pragma unroll
    for (int st = 8; st > 0; st >>= 1)
#pragma unroll
      for (int i = 0; i < 8; ++i) if (i < st) tsum[i] += tsum[i + st];
    l_r += tsum[0] + __shfl_xor(tsum[0], 32);

    unsigned pw0[8], pw1[8];
#pragma unroll
    for (int j = 0; j < 8; ++j) {
      pw0[j] = cvt_pk_bf16(s0[2 * j], s0[2 * j + 1]);
      pw1[j] = cvt_pk_bf16(s1[2 * j], s1[2 * j + 1]);
    }
    short8 paf[4];
    { u32x4 u; u[0]=pw0[0]; u[1]=pw0[1]; u[2]=pw0[2]; u[3]=pw0[3]; paf[0]=__builtin_bit_cast(short8,u); }
    { u32x4 u; u[0]=pw0[4]; u[1]=pw0[5]; u[2]=pw0[6]; u[3]=pw0[7]; paf[1]=__builtin_bit_cast(short8,u); }
    { u32x4 u; u[0]=pw1[0]; u[1]=pw1[1]; u[2]=pw1[2]; u[3]=pw1[3]; paf[2]=__builtin_bit_cast(short8,u); }
    { u32x4 u; u[0]=pw1[4]; u[1]=pw1[5]; u[2]=pw1[6]; u[3]=pw1[7]; paf[3]=__builtin_bit_cast(short8,u); }

    __builtin_amdgcn_s_setprio(1);
#pragma unroll
    for (int ts2 = 0; ts2 < 4; ++ts2) {
#pragma unroll
      for (int dn = 0; dn < 4; ++dn) {
        int row = dn * 32 + l31;
        int ch = ((2 * ts2 + hi) ^ (row & 7)) * 8;
        short8 vf = *(const short8*)&Vs[cur][row * 64 + ch];
        o[dn] = __builtin_amdgcn_mfma_f32_32x32x16_bf16(paf[ts2], vf, o[dn], 0, 0, 0);
      }
    }
    __builtin_amdgcn_s_setprio(0);

    BAR;
    if (t0 + 128 < N_) stage(cur, t0 + 128);
    cur ^= 1;
  }

  float linv = 1.0f / l_r;
#pragma unroll
  for (int r = 0; r < 16; ++r) {
    int qrow = (r & 3) + 8 * (r >> 2) + 4 * hi;
    float li = __shfl(linv, qrow);
    size_t rowg = (size_t)(b * N_ + q0 + qrow) * D_ + h * HD_;
#pragma unroll
    for (int dn = 0; dn < 4; ++dn)
      Y[rowg + dn * 32 + l31] = f2bf(o[dn][r] * li);
  }
}

extern "C" void kernel_launch(void* const* d_in, const int* in_sizes, int n_in,
                              void* d_out, int out_size, void* d_ws, size_t ws_size,
                              hipStream_t stream) {
  const float* x   = (const float*)d_in[0];
  const float* Wq  = (const float*)d_in[1];
  const float* Wkv = (const float*)d_in[2];
  const float* Wo  = (const float*)d_in[3];

  unsigned char* ws = (unsigned char*)d_ws;
  size_t off = 0;
  auto alloc = [&](size_t bytes) { void* p = ws + off; off += bytes; return p; };
  unsigned short* xb   = (unsigned short*)alloc((size_t)M_ * D_ * 2);   // reused as y
  unsigned short* wqt  = (unsigned short*)alloc((size_t)D_ * D_ * 2);   // [2048][2048]
  unsigned short* wkvt = (unsigned short*)alloc((size_t)KVC * D_ * 2);  // adjacent rows 2048..2303
  unsigned short* wot  = (unsigned short*)alloc((size_t)D_ * D_ * 2);
  unsigned short* qb   = (unsigned short*)alloc((size_t)M_ * D_ * 2);
  unsigned short* kvb  = (unsigned short*)alloc((size_t)M_ * KVC * 2);
  unsigned short* vt   = (unsigned short*)alloc((size_t)B_ * HD_ * N_ * 2);
  (void)ws_size; (void)in_sizes; (void)n_in; (void)out_size;

  cvt_bf16_kernel<<<(M_ * D_ / 8 + 255) / 256, 256, 0, stream>>>(x, xb, M_ * D_ / 8);
  transpose_cvt3<<<dim3(32, 68), 256, 0, stream>>>(Wq, Wkv, Wo, wqt, wkvt, wot);

  // (1/sqrt(128)) * log2(e): softmax runs in log2 domain inside attn_kernel
  const float scale = 0.12751743f;
  gemm256<0><<<dim3(NQKV / 256, M_ / 256), 512, 0, stream>>>(xb, wqt, qb, kvb, vt,
                                                             nullptr, scale);

  unsigned short* yb = xb;  // xb dead after gemm256<0>
  attn_kernel<<<dim3(N_ / 128, H_, B_), 256, 0, stream>>>(qb, kvb, vt, yb);

  gemm256<1><<<dim3(D_ / 256, M_ / 256), 512, 0, stream>>>(yb, wot, nullptr, nullptr, nullptr,
                                                           (float*)d_out, 1.0f);
}

// Round 23
// 323.982 us; speedup vs baseline: 1.0303x; 1.0063x over previous
//
#include <hip/hip_runtime.h>

typedef short short8 __attribute__((ext_vector_type(8)));
typedef float f32x4 __attribute__((ext_vector_type(4)));
typedef float f32x16 __attribute__((ext_vector_type(16)));
typedef unsigned int u32x4 __attribute__((ext_vector_type(4)));

#define B_   4
#define N_   2048
#define D_   2048
#define H_   16
#define HD_  128
#define M_   (B_ * N_)   // 8192
#define KVC  256         // kv projection cols (k 0..127 | v 128..255)
#define NQKV (D_ + KVC)  // 2304 fused output cols

__device__ __forceinline__ unsigned short f2bf(float f) {
  unsigned u = __builtin_bit_cast(unsigned, f);
  u = (u + 0x7FFFu + ((u >> 16) & 1u)) >> 16;   // RNE, finite inputs only
  return (unsigned short)u;
}

__device__ __forceinline__ void gl2lds16(const void* g, void* l) {
  __builtin_amdgcn_global_load_lds((const __attribute__((address_space(1))) void*)g,
                                   (__attribute__((address_space(3))) void*)l,
                                   16, 0, 0);
}

__device__ __forceinline__ unsigned cvt_pk_bf16(float lo, float hi) {
  unsigned r;
  asm volatile("v_cvt_pk_bf16_f32 %0, %1, %2" : "=v"(r) : "v"(lo), "v"(hi));
  return r;
}

#define LGKM0 do { asm volatile("s_waitcnt lgkmcnt(0)" ::: "memory"); \
                   __builtin_amdgcn_sched_barrier(0); } while (0)
#define BAR   do { __builtin_amdgcn_sched_barrier(0); __builtin_amdgcn_s_barrier(); \
                   __builtin_amdgcn_sched_barrier(0); } while (0)

// ---------------- elementwise f32 -> bf16 ----------------
__global__ __launch_bounds__(256) void cvt_bf16_kernel(const float* __restrict__ in,
                                                       unsigned short* __restrict__ out,
                                                       int n8) {
  int i = blockIdx.x * 256 + threadIdx.x;
  if (i >= n8) return;
  float4 a = ((const float4*)in)[i * 2];
  float4 b = ((const float4*)in)[i * 2 + 1];
  u32x4 u;
  u[0] = cvt_pk_bf16(a.x, a.y);
  u[1] = cvt_pk_bf16(a.z, a.w);
  u[2] = cvt_pk_bf16(b.x, b.y);
  u[3] = cvt_pk_bf16(b.z, b.w);
  ((short8*)out)[i] = __builtin_bit_cast(short8, u);
}

// ------- fused f32 [R][C] -> bf16 [C][R] for Wq | Wkv | Wo (one launch) -------
__global__ __launch_bounds__(256) void transpose_cvt3(const float* __restrict__ Wq,
                                                      const float* __restrict__ Wkv,
                                                      const float* __restrict__ Wo,
                                                      unsigned short* __restrict__ wqt,
                                                      unsigned short* __restrict__ wkvt,
                                                      unsigned short* __restrict__ wot) {
  __shared__ float tile[64][65];
  const float* in; unsigned short* out; int C, cy;
  if (blockIdx.y < 32)      { in = Wq;  out = wqt;  C = D_;  cy = blockIdx.y; }
  else if (blockIdx.y < 36) { in = Wkv; out = wkvt; C = KVC; cy = blockIdx.y - 32; }
  else                      { in = Wo;  out = wot;  C = D_;  cy = blockIdx.y - 36; }
  const int R = D_;
  int r0 = blockIdx.x * 64, c0 = cy * 64;
  int t = threadIdx.x;
  int tr = t >> 4, tc4 = (t & 15) * 4;
#pragma unroll
  for (int it = 0; it < 4; ++it) {
    int r = it * 16 + tr;
    float4 v = *(const float4*)(in + (size_t)(r0 + r) * C + c0 + tc4);
    tile[r][tc4 + 0] = v.x; tile[r][tc4 + 1] = v.y;
    tile[r][tc4 + 2] = v.z; tile[r][tc4 + 3] = v.w;
  }
  __syncthreads();
#pragma unroll
  for (int it = 0; it < 4; ++it) {
    int oc = it * 16 + tr;   // input col = output row
    ushort4 o;
    o.x = f2bf(tile[tc4 + 0][oc]);
    o.y = f2bf(tile[tc4 + 1][oc]);
    o.z = f2bf(tile[tc4 + 2][oc]);
    o.w = f2bf(tile[tc4 + 3][oc]);
    *(ushort4*)(out + (size_t)(c0 + oc) * R + r0 + tc4) = o;
  }
}

// ============ 256x256 8-phase GEMM (T2+T3+T4+T5), C = A @ Bt^T ============
// (R22 verified state, incl. fused transpose_v in MODE 0 epilogue)
template <int MODE>   // 0: qkv (q scaled -> qb; k -> kvb; v -> vt^T)   1: fp32 out
__global__ __launch_bounds__(512, 2) void gemm256(const unsigned short* __restrict__ A,
                                                  const unsigned short* __restrict__ Bt,
                                                  unsigned short* __restrict__ qb,
                                                  unsigned short* __restrict__ kvb,
                                                  unsigned short* __restrict__ vt,
                                                  float* __restrict__ fout,
                                                  float sq) {
  constexpr int BK = 64, K = D_, NT = K / BK;   // 32 K-tiles
  __shared__ __align__(16) unsigned short lds[2][4][128 * 64];   // 128 KB
  const int tid = threadIdx.x;
  const int lane = tid & 63;
  const int w = tid >> 6;               // 8 waves
  const int wr = w >> 2, wc = w & 3;    // 2 x 4
  const int l15 = lane & 15, lg = lane >> 4;
  const int row0 = blockIdx.y * 256, col0 = blockIdx.x * 256;

  f32x4 acc[8][4] = {};
  short8 bf[8];   // B fragments: held across the 4 phases of a K-tile
  short8 af[4];   // A fragments: per-phase quad

  auto stage = [&](int buf, int kind, int t) {   // kind: 0,1=A half; 2,3=B half
    const unsigned short* src = (kind < 2) ? A : Bt;
    const int base = (kind < 2) ? (row0 + kind * 128) : (col0 + (kind - 2) * 128);
#pragma unroll
    for (int ld = 0; ld < 2; ++ld) {
      int e = ld * 512 + tid;
      int r = e >> 3, c = e & 7;
      int csw = c ^ (r & 7);
      gl2lds16(src + (size_t)(base + r) * K + t * BK + csw * 8,
               &lds[buf][kind][(e - lane) * 8]);
    }
  };
  auto readB = [&](int buf) {
#pragma unroll
    for (int n = 0; n < 4; ++n)
#pragma unroll
      for (int kk = 0; kk < 2; ++kk) {
        int row = (wc & 1) * 64 + n * 16 + l15;
        int ch = (kk * 4 + lg) ^ (row & 7);
        bf[n * 2 + kk] = *(const short8*)&lds[buf][2 + (wc >> 1)][row * 64 + ch * 8];
      }
  };
  auto readA = [&](int buf, int q) {
#pragma unroll
    for (int mi = 0; mi < 2; ++mi)
#pragma unroll
      for (int kk = 0; kk < 2; ++kk) {
        int row = (q * 2 + mi) * 16 + l15;
        int ch = (kk * 4 + lg) ^ (row & 7);
        af[mi * 2 + kk] = *(const short8*)&lds[buf][wr][row * 64 + ch * 8];
      }
  };
  auto mfmaQ = [&](int q) {
    __builtin_amdgcn_s_setprio(1);
#pragma unroll
    for (int mi = 0; mi < 2; ++mi)
#pragma unroll
      for (int n = 0; n < 4; ++n)
#pragma unroll
        for (int kk = 0; kk < 2; ++kk)
          acc[q * 2 + mi][n] = __builtin_amdgcn_mfma_f32_16x16x32_bf16(
              af[mi * 2 + kk], bf[n * 2 + kk], acc[q * 2 + mi][n], 0, 0, 0);
    __builtin_amdgcn_s_setprio(0);
  };

  // prologue: tile0 all 4 halves (8 loads), then tile1 B halves (4 loads)
  stage(0, 0, 0); stage(0, 1, 0); stage(0, 2, 0); stage(0, 3, 0);
  stage(1, 2, 1); stage(1, 3, 1);

  for (int t = 0; t < NT; t += 2) {
    const bool gY = (t + 2 < NT), gZ = (t + 3 < NT);
    // ---- phase 1 (tile t, buf0, quad 0) ----
    asm volatile("s_waitcnt vmcnt(4)" ::: "memory");
    BAR;
    stage(1, 0, t + 1);
    readB(0); readA(0, 0);
    LGKM0; mfmaQ(0); BAR;
    // ---- phase 2 ----
    stage(1, 1, t + 1);
    readA(0, 1); LGKM0; mfmaQ(1); BAR;
    // ---- phase 3 ----
    if (gY) stage(0, 2, t + 2);
    readA(0, 2); LGKM0; mfmaQ(2); BAR;
    // ---- phase 4 ----
    if (gY) stage(0, 3, t + 2);
    readA(0, 3); LGKM0; mfmaQ(3); BAR;
    // ---- phase 5 (tile t+1, buf1, quad 0) ----
    if (gZ) { asm volatile("s_waitcnt vmcnt(4)" ::: "memory"); }
    else    { asm volatile("s_waitcnt vmcnt(0)" ::: "memory"); }
    BAR;
    if (gY) stage(0, 0, t + 2);
    readB(1); readA(1, 0);
    LGKM0; mfmaQ(0); BAR;
    // ---- phase 6 ----
    if (gY) stage(0, 1, t + 2);
    readA(1, 1); LGKM0; mfmaQ(1); BAR;
    // ---- phase 7 ----
    if (gZ) stage(1, 2, t + 3);
    readA(1, 2); LGKM0; mfmaQ(2); BAR;
    // ---- phase 8 ----
    if (gZ) stage(1, 3, t + 3);
    readA(1, 3); LGKM0; mfmaQ(3); BAR;
  }

  // ---- epilogue ----
  if (MODE == 0) {
    if (col0 < D_) {
      // q block: scaled bf16 -> qb
#pragma unroll
      for (int m = 0; m < 8; ++m)
#pragma unroll
        for (int n = 0; n < 4; ++n)
#pragma unroll
          for (int r = 0; r < 4; ++r) {
            int row = row0 + wr * 128 + m * 16 + lg * 4 + r;
            int col = col0 + wc * 64 + n * 16 + l15;
            qb[(size_t)row * D_ + col] = f2bf(acc[m][n][r] * sq);
          }
    } else {
      // kv block: k (col<128) -> kvb rows; v (col>=128) -> vt[b][d][t], pi-permuted.
#pragma unroll
      for (int m = 0; m < 8; ++m) {
        int trow0 = row0 + wr * 128 + m * 16 + lg * 4;
        int b = trow0 >> 11;
        int t4 = (trow0 & 2047) >> 2;          // 4-block index within batch
        int bm = t4 & 3;
        int p = (bm == 1 || bm == 2) ? (t4 ^ 3) : t4;
#pragma unroll
        for (int n = 0; n < 4; ++n) {
          int col = wc * 64 + n * 16 + l15;
          if (col < 128) {
#pragma unroll
            for (int r = 0; r < 4; ++r)
              kvb[(size_t)(trow0 + r) * KVC + col] = f2bf(acc[m][n][r]);
          } else {
            ushort4 v4;
            v4.x = f2bf(acc[m][n][0]); v4.y = f2bf(acc[m][n][1]);
            v4.z = f2bf(acc[m][n][2]); v4.w = f2bf(acc[m][n][3]);
            *(ushort4*)&vt[((size_t)(b * HD_ + col - 128)) * N_ + p * 4] = v4;
          }
        }
      }
    }
  } else {
#pragma unroll
    for (int m = 0; m < 8; ++m)
#pragma unroll
      for (int n = 0; n < 4; ++n)
#pragma unroll
        for (int r = 0; r < 4; ++r) {
          int row = row0 + wr * 128 + m * 16 + lg * 4 + r;
          int col = col0 + wc * 64 + n * 16 + l15;
          fout[(size_t)row * D_ + col] = acc[m][n][r];
        }
  }
}

// ---------------- flash attention (MQA), 32x32 swapped-QK^T, 8 waves/block ----------
// Same per-wave code as the R20/R22 verified kernel; pure parameter change:
// 512 threads (8 waves) share the same 64KB double-buffered LDS -> 2 blocks/CU =
// 4 waves/SIMD (vs 2), and staging drops to 4 gl2lds/thread/tile. Unlike R8's
// spilled attempt, __launch_bounds__(512,2) caps VGPR at 256 (demand ~95) -> no
// scratch. Counted vmcnt(4): tile t's 4 per-thread loads complete, t+1's stay
// in flight across the barrier.
__global__ __launch_bounds__(512, 2) void attn_kernel(const unsigned short* __restrict__ Q,
                                                      const unsigned short* __restrict__ KV,
                                                      const unsigned short* __restrict__ VT,
                                                      unsigned short* __restrict__ Y) {
  __shared__ __align__(16) unsigned short Ks[2][64 * HD_];   // [t][d] 16KB each, chunk^=(t&7)
  __shared__ __align__(16) unsigned short Vs[2][HD_ * 64];   // [d][t] 16KB each, chunk^=(d&7)
  const int tid = threadIdx.x;
  const int lane = tid & 63, w = tid >> 6;                // 8 waves
  const int l31 = lane & 31, hi = lane >> 5;
  const int ksw = l31 & 7;
  const int qt = blockIdx.x, h = blockIdx.y, b = blockIdx.z;
  const int q0 = qt * 256 + w * 32;        // warp's 32 q-rows

  short8 qf[8];
  {
    const unsigned short* qp = Q + (size_t)(b * N_ + q0 + l31) * D_ + h * HD_ + hi * 8;
#pragma unroll
    for (int kk = 0; kk < 8; ++kk) qf[kk] = *(const short8*)(qp + kk * 16);
  }

  f32x16 o[4] = {};
  float l_r = 0.f;

  // 4 loads per thread per tile (2 K-chunks + 2 V-chunks), src pre-swizzled
  auto stage = [&](int buf, int t0) {
#pragma unroll
    for (int s = 0; s < 2; ++s) {
      int e = s * 512 + tid;
      int r = e >> 4, c = e & 15;
      int csw = c ^ (r & 7);
      gl2lds16(KV + (size_t)(b * N_ + t0 + r) * KVC + csw * 8, &Ks[buf][(e - lane) * 8]);
    }
#pragma unroll
    for (int s = 0; s < 2; ++s) {
      int e = s * 512 + tid;
      int r = e >> 3, c = e & 7;
      int csw = c ^ (r & 7);
      gl2lds16(VT + (size_t)(b * HD_ + r) * N_ + t0 + csw * 8, &Vs[buf][(e - lane) * 8]);
    }
  };

  stage(0, 0);
  stage(1, 64);
  int cur = 0;

  for (int t0 = 0; t0 < N_; t0 += 64) {
    if (t0 + 64 < N_) { asm volatile("s_waitcnt vmcnt(4)" ::: "memory"); }
    else              { asm volatile("s_waitcnt vmcnt(0)" ::: "memory"); }
    BAR;

    f32x16 s0 = {}, s1 = {};
    __builtin_amdgcn_s_setprio(1);
#pragma unroll
    for (int kk = 0; kk < 8; ++kk) {
      int ch = ((2 * kk + hi) ^ ksw) * 8;
      short8 kf0 = *(const short8*)&Ks[cur][(l31) * HD_ + ch];
      short8 kf1 = *(const short8*)&Ks[cur][(32 + l31) * HD_ + ch];
      s0 = __builtin_amdgcn_mfma_f32_32x32x16_bf16(kf0, qf[kk], s0, 0, 0, 0);
      s1 = __builtin_amdgcn_mfma_f32_32x32x16_bf16(kf1, qf[kk], s1, 0, 0, 0);
    }
    __builtin_amdgcn_s_setprio(0);

#pragma unroll
    for (int r = 0; r < 16; ++r) {
      s0[r] = __builtin_amdgcn_exp2f(s0[r]);
      s1[r] = __builtin_amdgcn_exp2f(s1[r]);
    }
    float tsum[16];
#pragma unroll
    for (int r = 0; r < 16; ++r) tsum[r] = s0[r] + s1[r];
#pragma unroll
    for (int st = 8; st > 0; st >>= 1)
#pragma unroll
      for (int i = 0; i < 8; ++i) if (i < st) tsum[i] += tsum[i + st];
    l_r += tsum[0] + __shfl_xor(tsum[0], 32);

    unsigned pw0[8], pw1[8];
#pragma unroll
    for (int j = 0; j < 8; ++j) {
      pw0[j] = cvt_pk_bf16(s0[2 * j], s0[2 * j + 1]);
      pw1[j] = cvt_pk_bf16(s1[2 * j], s1[2 * j + 1]);
    }
    short8 paf[4];
    { u32x4 u; u[0]=pw0[0]; u[1]=pw0[1]; u[2]=pw0[2]; u[3]=pw0[3]; paf[0]=__builtin_bit_cast(short8,u); }
    { u32x4 u; u[0]=pw0[4]; u[1]=pw0[5]; u[2]=pw0[6]; u[3]=pw0[7]; paf[1]=__builtin_bit_cast(short8,u); }
    { u32x4 u; u[0]=pw1[0]; u[1]=pw1[1]; u[2]=pw1[2]; u[3]=pw1[3]; paf[2]=__builtin_bit_cast(short8,u); }
    { u32x4 u; u[0]=pw1[4]; u[1]=pw1[5]; u[2]=pw1[6]; u[3]=pw1[7]; paf[3]=__builtin_bit_cast(short8,u); }

    __builtin_amdgcn_s_setprio(1);
#pragma unroll
    for (int ts2 = 0; ts2 < 4; ++ts2) {
#pragma unroll
      for (int dn = 0; dn < 4; ++dn) {
        int row = dn * 32 + l31;
        int ch = ((2 * ts2 + hi) ^ (row & 7)) * 8;
        short8 vf = *(const short8*)&Vs[cur][row * 64 + ch];
        o[dn] = __builtin_amdgcn_mfma_f32_32x32x16_bf16(paf[ts2], vf, o[dn], 0, 0, 0);
      }
    }
    __builtin_amdgcn_s_setprio(0);

    BAR;
    if (t0 + 128 < N_) stage(cur, t0 + 128);
    cur ^= 1;
  }

  float linv = 1.0f / l_r;
#pragma unroll
  for (int r = 0; r < 16; ++r) {
    int qrow = (r & 3) + 8 * (r >> 2) + 4 * hi;
    float li = __shfl(linv, qrow);
    size_t rowg = (size_t)(b * N_ + q0 + qrow) * D_ + h * HD_;
#pragma unroll
    for (int dn = 0; dn < 4; ++dn)
      Y[rowg + dn * 32 + l31] = f2bf(o[dn][r] * li);
  }
}

extern "C" void kernel_launch(void* const* d_in, const int* in_sizes, int n_in,
                              void* d_out, int out_size, void* d_ws, size_t ws_size,
                              hipStream_t stream) {
  const float* x   = (const float*)d_in[0];
  const float* Wq  = (const float*)d_in[1];
  const float* Wkv = (const float*)d_in[2];
  const float* Wo  = (const float*)d_in[3];

  unsigned char* ws = (unsigned char*)d_ws;
  size_t off = 0;
  auto alloc = [&](size_t bytes) { void* p = ws + off; off += bytes; return p; };
  unsigned short* xb   = (unsigned short*)alloc((size_t)M_ * D_ * 2);   // reused as y
  unsigned short* wqt  = (unsigned short*)alloc((size_t)D_ * D_ * 2);   // [2048][2048]
  unsigned short* wkvt = (unsigned short*)alloc((size_t)KVC * D_ * 2);  // adjacent rows 2048..2303
  unsigned short* wot  = (unsigned short*)alloc((size_t)D_ * D_ * 2);
  unsigned short* qb   = (unsigned short*)alloc((size_t)M_ * D_ * 2);
  unsigned short* kvb  = (unsigned short*)alloc((size_t)M_ * KVC * 2);
  unsigned short* vt   = (unsigned short*)alloc((size_t)B_ * HD_ * N_ * 2);
  (void)ws_size; (void)in_sizes; (void)n_in; (void)out_size;

  cvt_bf16_kernel<<<(M_ * D_ / 8 + 255) / 256, 256, 0, stream>>>(x, xb, M_ * D_ / 8);
  transpose_cvt3<<<dim3(32, 68), 256, 0, stream>>>(Wq, Wkv, Wo, wqt, wkvt, wot);

  // (1/sqrt(128)) * log2(e): softmax runs in log2 domain inside attn_kernel
  const float scale = 0.12751743f;
  gemm256<0><<<dim3(NQKV / 256, M_ / 256), 512, 0, stream>>>(xb, wqt, qb, kvb, vt,
                                                             nullptr, scale);

  unsigned short* yb = xb;  // xb dead after gemm256<0>
  attn_kernel<<<dim3(N_ / 256, H_, B_), 512, 0, stream>>>(qb, kvb, vt, yb);

  gemm256<1><<<dim3(D_ / 256, M_ / 256), 512, 0, stream>>>(yb, wot, nullptr, nullptr, nullptr,
                                                           (float*)d_out, 1.0f);
}

// Round 24
// 323.472 us; speedup vs baseline: 1.0320x; 1.0016x over previous
//
#include <hip/hip_runtime.h>

typedef short short8 __attribute__((ext_vector_type(8)));
typedef float f32x4 __attribute__((ext_vector_type(4)));
typedef float f32x16 __attribute__((ext_vector_type(16)));
typedef unsigned int u32x4 __attribute__((ext_vector_type(4)));

#define B_   4
#define N_   2048
#define D_   2048
#define H_   16
#define HD_  128
#define M_   (B_ * N_)   // 8192
#define KVC  256         // kv buffer stride (k cols 0..127 used)
#define NQKV (D_ + KVC)

__device__ __forceinline__ unsigned short f2bf(float f) {
  unsigned u = __builtin_bit_cast(unsigned, f);
  u = (u + 0x7FFFu + ((u >> 16) & 1u)) >> 16;   // RNE, finite inputs only
  return (unsigned short)u;
}

__device__ __forceinline__ void gl2lds16(const void* g, void* l) {
  __builtin_amdgcn_global_load_lds((const __attribute__((address_space(1))) void*)g,
                                   (__attribute__((address_space(3))) void*)l,
                                   16, 0, 0);
}

__device__ __forceinline__ unsigned cvt_pk_bf16(float lo, float hi) {
  unsigned r;
  asm volatile("v_cvt_pk_bf16_f32 %0, %1, %2" : "=v"(r) : "v"(lo), "v"(hi));
  return r;
}

#define LGKM0 do { asm volatile("s_waitcnt lgkmcnt(0)" ::: "memory"); \
                   __builtin_amdgcn_sched_barrier(0); } while (0)
#define BAR   do { __builtin_amdgcn_sched_barrier(0); __builtin_amdgcn_s_barrier(); \
                   __builtin_amdgcn_sched_barrier(0); } while (0)

// ---------------- elementwise f32 -> bf16 ----------------
__global__ __launch_bounds__(256) void cvt_bf16_kernel(const float* __restrict__ in,
                                                       unsigned short* __restrict__ out,
                                                       int n8) {
  int i = blockIdx.x * 256 + threadIdx.x;
  if (i >= n8) return;
  float4 a = ((const float4*)in)[i * 2];
  float4 b = ((const float4*)in)[i * 2 + 1];
  u32x4 u;
  u[0] = cvt_pk_bf16(a.x, a.y);
  u[1] = cvt_pk_bf16(a.z, a.w);
  u[2] = cvt_pk_bf16(b.x, b.y);
  u[3] = cvt_pk_bf16(b.z, b.w);
  ((short8*)out)[i] = __builtin_bit_cast(short8, u);
}

// ------- fused f32 [R][C] -> bf16 [C][R] for Wq | Wkv | Wo (one launch) -------
__global__ __launch_bounds__(256) void transpose_cvt3(const float* __restrict__ Wq,
                                                      const float* __restrict__ Wkv,
                                                      const float* __restrict__ Wo,
                                                      unsigned short* __restrict__ wqt,
                                                      unsigned short* __restrict__ wkvt,
                                                      unsigned short* __restrict__ wot) {
  __shared__ float tile[64][65];
  const float* in; unsigned short* out; int C, cy;
  if (blockIdx.y < 32)      { in = Wq;  out = wqt;  C = D_;  cy = blockIdx.y; }
  else if (blockIdx.y < 36) { in = Wkv; out = wkvt; C = KVC; cy = blockIdx.y - 32; }
  else                      { in = Wo;  out = wot;  C = D_;  cy = blockIdx.y - 36; }
  const int R = D_;
  int r0 = blockIdx.x * 64, c0 = cy * 64;
  int t = threadIdx.x;
  int tr = t >> 4, tc4 = (t & 15) * 4;
#pragma unroll
  for (int it = 0; it < 4; ++it) {
    int r = it * 16 + tr;
    float4 v = *(const float4*)(in + (size_t)(r0 + r) * C + c0 + tc4);
    tile[r][tc4 + 0] = v.x; tile[r][tc4 + 1] = v.y;
    tile[r][tc4 + 2] = v.z; tile[r][tc4 + 3] = v.w;
  }
  __syncthreads();
#pragma unroll
  for (int it = 0; it < 4; ++it) {
    int oc = it * 16 + tr;   // input col = output row
    ushort4 o;
    o.x = f2bf(tile[tc4 + 0][oc]);
    o.y = f2bf(tile[tc4 + 1][oc]);
    o.z = f2bf(tile[tc4 + 2][oc]);
    o.w = f2bf(tile[tc4 + 3][oc]);
    *(ushort4*)(out + (size_t)(c0 + oc) * R + r0 + tc4) = o;
  }
}

// ============ 256x256 8-phase GEMM (T2+T3+T4+T5), C = A @ Bt^T ============
// 1 block/CU (128KB LDS). Grids sized to exactly 256 blocks for 1-round packing.
template <int MODE>   // 0: bf16 out scaled -> obf   1: fp32 out -> fout
__global__ __launch_bounds__(512, 2) void gemm256(const unsigned short* __restrict__ A,
                                                  const unsigned short* __restrict__ Bt,
                                                  unsigned short* __restrict__ obf,
                                                  float* __restrict__ fout,
                                                  float sq) {
  constexpr int BK = 64, K = D_, NT = K / BK;   // 32 K-tiles
  __shared__ __align__(16) unsigned short lds[2][4][128 * 64];   // 128 KB
  const int tid = threadIdx.x;
  const int lane = tid & 63;
  const int w = tid >> 6;               // 8 waves
  const int wr = w >> 2, wc = w & 3;    // 2 x 4
  const int l15 = lane & 15, lg = lane >> 4;
  const int row0 = blockIdx.y * 256, col0 = blockIdx.x * 256;

  f32x4 acc[8][4] = {};
  short8 bf[8];   // B fragments: held across the 4 phases of a K-tile
  short8 af[4];   // A fragments: per-phase quad

  auto stage = [&](int buf, int kind, int t) {   // kind: 0,1=A half; 2,3=B half
    const unsigned short* src = (kind < 2) ? A : Bt;
    const int base = (kind < 2) ? (row0 + kind * 128) : (col0 + (kind - 2) * 128);
#pragma unroll
    for (int ld = 0; ld < 2; ++ld) {
      int e = ld * 512 + tid;
      int r = e >> 3, c = e & 7;
      int csw = c ^ (r & 7);
      gl2lds16(src + (size_t)(base + r) * K + t * BK + csw * 8,
               &lds[buf][kind][(e - lane) * 8]);
    }
  };
  auto readB = [&](int buf) {
#pragma unroll
    for (int n = 0; n < 4; ++n)
#pragma unroll
      for (int kk = 0; kk < 2; ++kk) {
        int row = (wc & 1) * 64 + n * 16 + l15;
        int ch = (kk * 4 + lg) ^ (row & 7);
        bf[n * 2 + kk] = *(const short8*)&lds[buf][2 + (wc >> 1)][row * 64 + ch * 8];
      }
  };
  auto readA = [&](int buf, int q) {
#pragma unroll
    for (int mi = 0; mi < 2; ++mi)
#pragma unroll
      for (int kk = 0; kk < 2; ++kk) {
        int row = (q * 2 + mi) * 16 + l15;
        int ch = (kk * 4 + lg) ^ (row & 7);
        af[mi * 2 + kk] = *(const short8*)&lds[buf][wr][row * 64 + ch * 8];
      }
  };
  auto mfmaQ = [&](int q) {
    __builtin_amdgcn_s_setprio(1);
#pragma unroll
    for (int mi = 0; mi < 2; ++mi)
#pragma unroll
      for (int n = 0; n < 4; ++n)
#pragma unroll
        for (int kk = 0; kk < 2; ++kk)
          acc[q * 2 + mi][n] = __builtin_amdgcn_mfma_f32_16x16x32_bf16(
              af[mi * 2 + kk], bf[n * 2 + kk], acc[q * 2 + mi][n], 0, 0, 0);
    __builtin_amdgcn_s_setprio(0);
  };

  // prologue: tile0 all 4 halves (8 loads), then tile1 B halves (4 loads)
  stage(0, 0, 0); stage(0, 1, 0); stage(0, 2, 0); stage(0, 3, 0);
  stage(1, 2, 1); stage(1, 3, 1);

  for (int t = 0; t < NT; t += 2) {
    const bool gY = (t + 2 < NT), gZ = (t + 3 < NT);
    // ---- phase 1 (tile t, buf0, quad 0) ----
    asm volatile("s_waitcnt vmcnt(4)" ::: "memory");
    BAR;
    stage(1, 0, t + 1);
    readB(0); readA(0, 0);
    LGKM0; mfmaQ(0); BAR;
    // ---- phase 2 ----
    stage(1, 1, t + 1);
    readA(0, 1); LGKM0; mfmaQ(1); BAR;
    // ---- phase 3 ----
    if (gY) stage(0, 2, t + 2);
    readA(0, 2); LGKM0; mfmaQ(2); BAR;
    // ---- phase 4 ----
    if (gY) stage(0, 3, t + 2);
    readA(0, 3); LGKM0; mfmaQ(3); BAR;
    // ---- phase 5 (tile t+1, buf1, quad 0) ----
    if (gZ) { asm volatile("s_waitcnt vmcnt(4)" ::: "memory"); }
    else    { asm volatile("s_waitcnt vmcnt(0)" ::: "memory"); }
    BAR;
    if (gY) stage(0, 0, t + 2);
    readB(1); readA(1, 0);
    LGKM0; mfmaQ(0); BAR;
    // ---- phase 6 ----
    if (gY) stage(0, 1, t + 2);
    readA(1, 1); LGKM0; mfmaQ(1); BAR;
    // ---- phase 7 ----
    if (gZ) stage(1, 2, t + 3);
    readA(1, 2); LGKM0; mfmaQ(2); BAR;
    // ---- phase 8 ----
    if (gZ) stage(1, 3, t + 3);
    readA(1, 3); LGKM0; mfmaQ(3); BAR;
  }

  // ---- epilogue ----
#pragma unroll
  for (int m = 0; m < 8; ++m)
#pragma unroll
    for (int n = 0; n < 4; ++n)
#pragma unroll
      for (int r = 0; r < 4; ++r) {
        int row = row0 + wr * 128 + m * 16 + lg * 4 + r;
        int col = col0 + wc * 64 + n * 16 + l15;
        if (MODE == 0) obf[(size_t)row * D_ + col] = f2bf(acc[m][n][r] * sq);
        else           fout[(size_t)row * D_ + col] = acc[m][n][r];
      }
}

// ---------- kv GEMM: [k|v] = xb @ Wkv^T, 128x128 tile, 4 waves, 2-barrier ----------
// Small (8.6 GF): grid (2,64) = 128 blocks. col0=0 -> k cols -> kvb (stride KVC);
// col0=128 -> v cols -> vt[b][d][t] with pi 4-block permutation (same algebra as
// the R22-verified fused epilogue; each lane's r=0..3 spans one aligned t 4-block).
__global__ __launch_bounds__(256) void gemm_kv(const unsigned short* __restrict__ A,
                                               const unsigned short* __restrict__ Bt,
                                               unsigned short* __restrict__ kvb,
                                               unsigned short* __restrict__ vt) {
  constexpr int BM = 128, BN = 128, BK = 64, K = D_;
  __shared__ __align__(16) unsigned short As[BM * BK];
  __shared__ __align__(16) unsigned short Bs[BN * BK];
  const int tid = threadIdx.x;
  const int lane = tid & 63;
  const int w = tid >> 6;
  const int wr = w >> 1, wc = w & 1;       // 2x2 waves, each 64x64
  const int l15 = lane & 15, lg = lane >> 4;
  const int row0 = blockIdx.y * BM, col0 = blockIdx.x * BN;

  f32x4 acc[4][4] = {};

  for (int k0 = 0; k0 < K; k0 += BK) {
    __syncthreads();
#pragma unroll
    for (int s = 0; s < 4; ++s) {          // A tile: 128 x 64, 8 chunks/row
      int e = s * 256 + tid;
      int r = e >> 3, c = e & 7;
      gl2lds16(A + (size_t)(row0 + r) * K + k0 + c * 8, As + (e - lane) * 8);
    }
#pragma unroll
    for (int s = 0; s < 4; ++s) {          // B tile: 128 x 64
      int e = s * 256 + tid;
      int r = e >> 3, c = e & 7;
      gl2lds16(Bt + (size_t)(col0 + r) * K + k0 + c * 8, Bs + (e - lane) * 8);
    }
    __syncthreads();

#pragma unroll
    for (int kk = 0; kk < 2; ++kk) {
      short8 af[4], bfr[4];
#pragma unroll
      for (int m = 0; m < 4; ++m)
        af[m] = *(const short8*)&As[(wr * 64 + m * 16 + l15) * BK + kk * 32 + lg * 8];
#pragma unroll
      for (int n = 0; n < 4; ++n)
        bfr[n] = *(const short8*)&Bs[(wc * 64 + n * 16 + l15) * BK + kk * 32 + lg * 8];
#pragma unroll
      for (int m = 0; m < 4; ++m)
#pragma unroll
        for (int n = 0; n < 4; ++n)
          acc[m][n] = __builtin_amdgcn_mfma_f32_16x16x32_bf16(af[m], bfr[n], acc[m][n], 0, 0, 0);
    }
  }

  const bool isk = (col0 < 128);
#pragma unroll
  for (int m = 0; m < 4; ++m) {
    int trow0 = row0 + wr * 64 + m * 16 + lg * 4;
    int b = trow0 >> 11;
    int t4 = (trow0 & 2047) >> 2;
    int bm = t4 & 3;
    int p = (bm == 1 || bm == 2) ? (t4 ^ 3) : t4;
#pragma unroll
    for (int n = 0; n < 4; ++n) {
      int col = col0 + wc * 64 + n * 16 + l15;
      if (isk) {
#pragma unroll
        for (int r = 0; r < 4; ++r)
          kvb[(size_t)(trow0 + r) * KVC + col] = f2bf(acc[m][n][r]);
      } else {
        ushort4 v4;
        v4.x = f2bf(acc[m][n][0]); v4.y = f2bf(acc[m][n][1]);
        v4.z = f2bf(acc[m][n][2]); v4.w = f2bf(acc[m][n][3]);
        *(ushort4*)&vt[((size_t)(b * HD_ + col - 128)) * N_ + p * 4] = v4;
      }
    }
  }
}

// ---------------- flash attention (MQA), 32x32 swapped-QK^T, 4 waves/block ----------
// R22-verified kernel (per-kernel best: 155us; 8-wave variant measured 159.5).
__global__ __launch_bounds__(256, 2) void attn_kernel(const unsigned short* __restrict__ Q,
                                                      const unsigned short* __restrict__ KV,
                                                      const unsigned short* __restrict__ VT,
                                                      unsigned short* __restrict__ Y) {
  __shared__ __align__(16) unsigned short Ks[2][64 * HD_];   // [t][d] 16KB each, chunk^=(t&7)
  __shared__ __align__(16) unsigned short Vs[2][HD_ * 64];   // [d][t] 16KB each, chunk^=(d&7)
  const int tid = threadIdx.x;
  const int lane = tid & 63, w = tid >> 6;                // 4 waves
  const int l31 = lane & 31, hi = lane >> 5;
  const int ksw = l31 & 7;
  const int qt = blockIdx.x, h = blockIdx.y, b = blockIdx.z;
  const int q0 = qt * 128 + w * 32;        // warp's 32 q-rows

  short8 qf[8];
  {
    const unsigned short* qp = Q + (size_t)(b * N_ + q0 + l31) * D_ + h * HD_ + hi * 8;
#pragma unroll
    for (int kk = 0; kk < 8; ++kk) qf[kk] = *(const short8*)(qp + kk * 16);
  }

  f32x16 o[4] = {};
  float l_r = 0.f;

  auto stage = [&](int buf, int t0) {
#pragma unroll
    for (int s = 0; s < 4; ++s) {
      int e = s * 256 + tid;
      int r = e >> 4, c = e & 15;
      int csw = c ^ (r & 7);
      gl2lds16(KV + (size_t)(b * N_ + t0 + r) * KVC + csw * 8, &Ks[buf][(e - lane) * 8]);
    }
#pragma unroll
    for (int s = 0; s < 4; ++s) {
      int e = s * 256 + tid;
      int r = e >> 3, c = e & 7;
      int csw = c ^ (r & 7);
      gl2lds16(VT + (size_t)(b * HD_ + r) * N_ + t0 + csw * 8, &Vs[buf][(e - lane) * 8]);
    }
  };

  stage(0, 0);
  stage(1, 64);
  int cur = 0;

  for (int t0 = 0; t0 < N_; t0 += 64) {
    if (t0 + 64 < N_) { asm volatile("s_waitcnt vmcnt(8)" ::: "memory"); }
    else              { asm volatile("s_waitcnt vmcnt(0)" ::: "memory"); }
    BAR;

    f32x16 s0 = {}, s1 = {};
    __builtin_amdgcn_s_setprio(1);
#pragma unroll
    for (int kk = 0; kk < 8; ++kk) {
      int ch = ((2 * kk + hi) ^ ksw) * 8;
      short8 kf0 = *(const short8*)&Ks[cur][(l31) * HD_ + ch];
      short8 kf1 = *(const short8*)&Ks[cur][(32 + l31) * HD_ + ch];
      s0 = __builtin_amdgcn_mfma_f32_32x32x16_bf16(kf0, qf[kk], s0, 0, 0, 0);
      s1 = __builtin_amdgcn_mfma_f32_32x32x16_bf16(kf1, qf[kk], s1, 0, 0, 0);
    }
    __builtin_amdgcn_s_setprio(0);

#pragma unroll
    for (int r = 0; r < 16; ++r) {
      s0[r] = __builtin_amdgcn_exp2f(s0[r]);
      s1[r] = __builtin_amdgcn_exp2f(s1[r]);
    }
    float tsum[16];
#pragma unroll
    for (int r = 0; r < 16; ++r) tsum[r] = s0[r] + s1[r];
#pragma unroll
    for (int st = 8; st > 0; st >>= 1)
#pragma unroll
      for (int i = 0; i < 8; ++i) if (i < st) tsum[i] += tsum[i + st];
    l_r += tsum[0] + __shfl_xor(tsum[0], 32);

    unsigned pw0[8], pw1[8];
#pragma unroll
    for (int j = 0; j < 8; ++j) {
      pw0[j] = cvt_pk_bf16(s0[2 * j], s0[2 * j + 1]);
      pw1[j] = cvt_pk_bf16(s1[2 * j], s1[2 * j + 1]);
    }
    short8 paf[4];
    { u32x4 u; u[0]=pw0[0]; u[1]=pw0[1]; u[2]=pw0[2]; u[3]=pw0[3]; paf[0]=__builtin_bit_cast(short8,u); }
    { u32x4 u; u[0]=pw0[4]; u[1]=pw0[5]; u[2]=pw0[6]; u[3]=pw0[7]; paf[1]=__builtin_bit_cast(short8,u); }
    { u32x4 u; u[0]=pw1[0]; u[1]=pw1[1]; u[2]=pw1[2]; u[3]=pw1[3]; paf[2]=__builtin_bit_cast(short8,u); }
    { u32x4 u; u[0]=pw1[4]; u[1]=pw1[5]; u[2]=pw1[6]; u[3]=pw1[7]; paf[3]=__builtin_bit_cast(short8,u); }

    __builtin_amdgcn_s_setprio(1);
#pragma unroll
    for (int ts2 = 0; ts2 < 4; ++ts2) {
#pragma unroll
      for (int dn = 0; dn < 4; ++dn) {
        int row = dn * 32 + l31;
        int ch = ((2 * ts2 + hi) ^ (row & 7)) * 8;
        short8 vf = *(const short8*)&Vs[cur][row * 64 + ch];
        o[dn] = __builtin_amdgcn_mfma_f32_32x32x16_bf16(paf[ts2], vf, o[dn], 0, 0, 0);
      }
    }
    __builtin_amdgcn_s_setprio(0);

    BAR;
    if (t0 + 128 < N_) stage(cur, t0 + 128);
    cur ^= 1;
  }

  float linv = 1.0f / l_r;
#pragma unroll
  for (int r = 0; r < 16; ++r) {
    int qrow = (r & 3) + 8 * (r >> 2) + 4 * hi;
    float li = __shfl(linv, qrow);
    size_t rowg = (size_t)(b * N_ + q0 + qrow) * D_ + h * HD_;
#pragma unroll
    for (int dn = 0; dn < 4; ++dn)
      Y[rowg + dn * 32 + l31] = f2bf(o[dn][r] * li);
  }
}

extern "C" void kernel_launch(void* const* d_in, const int* in_sizes, int n_in,
                              void* d_out, int out_size, void* d_ws, size_t ws_size,
                              hipStream_t stream) {
  const float* x   = (const float*)d_in[0];
  const float* Wq  = (const float*)d_in[1];
  const float* Wkv = (const float*)d_in[2];
  const float* Wo  = (const float*)d_in[3];

  unsigned char* ws = (unsigned char*)d_ws;
  size_t off = 0;
  auto alloc = [&](size_t bytes) { void* p = ws + off; off += bytes; return p; };
  unsigned short* xb   = (unsigned short*)alloc((size_t)M_ * D_ * 2);   // reused as y
  unsigned short* wqt  = (unsigned short*)alloc((size_t)D_ * D_ * 2);   // [2048][2048]
  unsigned short* wkvt = (unsigned short*)alloc((size_t)KVC * D_ * 2);
  unsigned short* wot  = (unsigned short*)alloc((size_t)D_ * D_ * 2);
  unsigned short* qb   = (unsigned short*)alloc((size_t)M_ * D_ * 2);
  unsigned short* kvb  = (unsigned short*)alloc((size_t)M_ * KVC * 2);
  unsigned short* vt   = (unsigned short*)alloc((size_t)B_ * HD_ * N_ * 2);
  (void)ws_size; (void)in_sizes; (void)n_in; (void)out_size;

  cvt_bf16_kernel<<<(M_ * D_ / 8 + 255) / 256, 256, 0, stream>>>(x, xb, M_ * D_ / 8);
  transpose_cvt3<<<dim3(32, 68), 256, 0, stream>>>(Wq, Wkv, Wo, wqt, wkvt, wot);

  // (1/sqrt(128)) * log2(e): softmax runs in log2 domain inside attn_kernel
  const float scale = 0.12751743f;
  gemm256<0><<<dim3(D_ / 256, M_ / 256), 512, 0, stream>>>(xb, wqt, qb, nullptr, scale);
  gemm_kv<<<dim3(2, M_ / 128), 256, 0, stream>>>(xb, wkvt, kvb, vt);

  unsigned short* yb = xb;  // xb dead after the two projection GEMMs
  attn_kernel<<<dim3(N_ / 128, H_, B_), 256, 0, stream>>>(qb, kvb, vt, yb);

  gemm256<1><<<dim3(D_ / 256, M_ / 256), 512, 0, stream>>>(yb, wot, nullptr,
                                                           (float*)d_out, 1.0f);
}